// Round 11
// baseline (159.025 us; speedup 1.0000x reference)
//
#include <hip/hip_runtime.h>
#include <hip/hip_bf16.h>

typedef __hip_bfloat16 bf16;
typedef __attribute__((ext_vector_type(8))) short short8;
typedef __attribute__((ext_vector_type(4))) float f32x4;
typedef __attribute__((ext_vector_type(16))) float f32x16;

#define MFMA16(a, b, c) __builtin_amdgcn_mfma_f32_16x16x32_bf16((a), (b), (c), 0, 0, 0)
#define MFMA32(a, b, c) __builtin_amdgcn_mfma_f32_32x32x16_bf16((a), (b), (c), 0, 0, 0)

// Problem constants
#define BATCH 2
#define NQ 2048
#define NKV 2048
#define HEADS 8
#define DHEAD 64
#define CQ 1024
#define CK 768
#define IDIM 512   // HEADS*DHEAD
#define SCALE 0.125f

__device__ __forceinline__ short8 ld8(const bf16* p) {
    return *(const short8*)p;
}

// async global->LDS, 16 bytes per lane. LDS dst must be wave-uniform base + lane*16.
__device__ __forceinline__ void async_ld16(const bf16* g, bf16* l) {
    __builtin_amdgcn_global_load_lds((__attribute__((address_space(1))) const void*)g,
                                     (__attribute__((address_space(3))) void*)l,
                                     16, 0, 0);
}

// ---------------------------------------------------------------------------
// Prologue: fp32->bf16 activation pack (blocks 0..3583, 8 floats/thread) +
// tiled weight transpose fp32(R,C) -> bf16(C,R) (blocks 3584..4031).
// ---------------------------------------------------------------------------
__global__ __launch_bounds__(256) void prologue(
    const float* __restrict__ x, const float* __restrict__ ctx,
    const float* __restrict__ Wq, const float* __restrict__ Wk,
    const float* __restrict__ Wv, const float* __restrict__ Wo,
    bf16* __restrict__ Xb, bf16* __restrict__ Cb,
    bf16* __restrict__ WqT, bf16* __restrict__ WkT,
    bf16* __restrict__ WvT, bf16* __restrict__ WoT) {
    __shared__ float tile[64][65];
    const int t = threadIdx.x;
    const int bx = blockIdx.x;

    if (bx < 3584) {
        int idx = bx * 256 + t;
        const int NX8 = (4096 * 1024) / 8;      // 524,288
        const float4* srcp;
        bf16* dstp;
        if (idx < NX8) {
            srcp = (const float4*)x + (size_t)idx * 2;
            dstp = Xb + (size_t)idx * 8;
        } else {
            int j = idx - NX8;                  // < 393,216
            srcp = (const float4*)ctx + (size_t)j * 2;
            dstp = Cb + (size_t)j * 8;
        }
        float4 v0 = srcp[0], v1 = srcp[1];
        bf16 tmp[8] = {__float2bfloat16(v0.x), __float2bfloat16(v0.y),
                       __float2bfloat16(v0.z), __float2bfloat16(v0.w),
                       __float2bfloat16(v1.x), __float2bfloat16(v1.y),
                       __float2bfloat16(v1.z), __float2bfloat16(v1.w)};
        *(short8*)dstp = *(short8*)tmp;
        return;
    }

    int tb = bx - 3584;   // 0..447
    const float* src; bf16* dst; int R, C, ti;
    if (tb < 128)      { src = Wq; dst = WqT; R = 1024; C = 512;  ti = tb; }
    else if (tb < 224) { src = Wk; dst = WkT; R = 768;  C = 512;  ti = tb - 128; }
    else if (tb < 320) { src = Wv; dst = WvT; R = 768;  C = 512;  ti = tb - 224; }
    else               { src = Wo; dst = WoT; R = 512;  C = 1024; ti = tb - 320; }
    const int tilesC = C >> 6;
    const int tr = ti / tilesC, tc = ti - tr * tilesC;

    {
        int row = t >> 4;
        int c4 = (t & 15) * 4;
#pragma unroll
        for (int p = 0; p < 4; ++p) {
            float4 v = *(const float4*)&src[(size_t)(tr * 64 + p * 16 + row) * C + tc * 64 + c4];
            tile[p * 16 + row][c4 + 0] = v.x;
            tile[p * 16 + row][c4 + 1] = v.y;
            tile[p * 16 + row][c4 + 2] = v.z;
            tile[p * 16 + row][c4 + 3] = v.w;
        }
    }
    __syncthreads();
    {
        int oc = t >> 2;
        int r0 = (t & 3) * 16;
        bf16 tmp[16];
#pragma unroll
        for (int j = 0; j < 16; ++j)
            tmp[j] = __float2bfloat16(tile[r0 + j][oc]);
        bf16* dp = dst + (size_t)(tc * 64 + oc) * R + tr * 64 + r0;
        *(short8*)dp = *(short8*)&tmp[0];
        *(short8*)(dp + 8) = *(short8*)&tmp[8];
    }
}

// ---------------------------------------------------------------------------
// Fused Q/K/V projection GEMM, 64x128 tiles, BK=64, XOR-swizzled LDS chunks,
// double-buffered. blockIdx.z: 0 -> Q, 1 -> K, 2 -> V^T epilogue.
// ---------------------------------------------------------------------------
__global__ __launch_bounds__(256) void qkv_gemm(
    const bf16* __restrict__ Xb, const bf16* __restrict__ Cb,
    const bf16* __restrict__ WqT, const bf16* __restrict__ WkT,
    const bf16* __restrict__ WvT,
    bf16* __restrict__ Qb, bf16* __restrict__ Kb, bf16* __restrict__ Vt) {
    __shared__ bf16 At[2][64 * 64];
    __shared__ bf16 Bts[2][128 * 64];

    const int z = blockIdx.z;
    const bf16* A  = (z == 0) ? Xb : Cb;
    const bf16* Bt = (z == 0) ? WqT : (z == 1) ? WkT : WvT;
    const int K = (z == 0) ? 1024 : 768;

    const int t = threadIdx.x;
    const int wave = t >> 6;
    const int lane = t & 63;
    const int n15 = lane & 15;
    const int quad = lane >> 4;
    const int wm = wave >> 1;
    const int wn = wave & 1;
    const int bm = blockIdx.y;     // 0..63
    const int bn = blockIdx.x;     // 0..3

    f32x4 acc[2][4] = {};

    const bf16* Ablk = A + (size_t)bm * 64 * K;
    const bf16* Bblk = Bt + (size_t)bn * 128 * K;

    int ar[2], ac[2], br[4], bc[4];
#pragma unroll
    for (int i = 0; i < 2; ++i) {
        int g = i * 256 + t;
        ar[i] = g >> 3; ac[i] = ((g & 7) ^ (ar[i] & 7)) * 8;
    }
#pragma unroll
    for (int i = 0; i < 4; ++i) {
        int g = i * 256 + t;
        br[i] = g >> 3; bc[i] = ((g & 7) ^ (br[i] & 7)) * 8;
    }

#pragma unroll
    for (int i = 0; i < 2; ++i)
        async_ld16(Ablk + ar[i] * K + ac[i], &At[0][(i * 256 + t) * 8]);
#pragma unroll
    for (int i = 0; i < 4; ++i)
        async_ld16(Bblk + br[i] * K + bc[i], &Bts[0][(i * 256 + t) * 8]);
    __syncthreads();

    for (int k0 = 0; k0 < K; k0 += 64) {
        const int p = (k0 >> 6) & 1;
        if (k0 + 64 < K) {
            const int q = p ^ 1;
            const int kn = k0 + 64;
#pragma unroll
            for (int i = 0; i < 2; ++i)
                async_ld16(Ablk + ar[i] * K + kn + ac[i], &At[q][(i * 256 + t) * 8]);
#pragma unroll
            for (int i = 0; i < 4; ++i)
                async_ld16(Bblk + br[i] * K + kn + bc[i], &Bts[q][(i * 256 + t) * 8]);
        }

#pragma unroll
        for (int kh = 0; kh < 2; ++kh) {
            short8 af[2], bfr[4];
#pragma unroll
            for (int mt = 0; mt < 2; ++mt) {
                int R = wm * 32 + mt * 16 + n15;
                af[mt] = ld8(&At[p][R * 64 + (((kh * 4 + quad) ^ (R & 7)) * 8)]);
            }
#pragma unroll
            for (int nt = 0; nt < 4; ++nt) {
                int R = wn * 64 + nt * 16 + n15;
                bfr[nt] = ld8(&Bts[p][R * 64 + (((kh * 4 + quad) ^ (R & 7)) * 8)]);
            }
#pragma unroll
            for (int mt = 0; mt < 2; ++mt)
#pragma unroll
                for (int nt = 0; nt < 4; ++nt)
                    acc[mt][nt] = MFMA16(af[mt], bfr[nt], acc[mt][nt]);
        }

        __syncthreads();
    }

    bf16* C = (z == 0) ? Qb : (z == 1) ? Kb : Vt;
#pragma unroll
    for (int mt = 0; mt < 2; ++mt) {
#pragma unroll
        for (int nt = 0; nt < 4; ++nt) {
            int col = bn * 128 + wn * 64 + nt * 16 + n15;
#pragma unroll
            for (int r = 0; r < 4; ++r) {
                int row = bm * 64 + wm * 32 + mt * 16 + quad * 4 + r;
                bf16 v = __float2bfloat16(acc[mt][nt][r]);
                if (z < 2) {
                    C[(size_t)row * 512 + col] = v;
                } else {
                    int b = row >> 11, j = row & 2047;
                    int h = col >> 6, d = col & 63;
                    C[(size_t)(((b << 3) + h) * 64 + d) * 2048 + j] = v;
                }
            }
        }
    }
}

// ---------------------------------------------------------------------------
// Final GEMM: out(4096,1024) = Ob(4096,512) @ WoT(1024,512)^T + bo, fp32 out.
// 64x128 tiles, BK=64, swizzled, double-buffered.
// ---------------------------------------------------------------------------
__global__ __launch_bounds__(256) void out_gemm(const bf16* __restrict__ A,
                                                const bf16* __restrict__ Bt,
                                                const float* __restrict__ bias,
                                                float* __restrict__ C) {
    const int K = 512, N = 1024;
    __shared__ bf16 At[2][64 * 64];
    __shared__ bf16 Bts[2][128 * 64];

    const int t = threadIdx.x;
    const int wave = t >> 6;
    const int lane = t & 63;
    const int n15 = lane & 15;
    const int quad = lane >> 4;
    const int wm = wave >> 1;
    const int wn = wave & 1;
    const int bm = blockIdx.y;     // 0..63
    const int bn = blockIdx.x;     // 0..7

    f32x4 acc[2][4] = {};

    const bf16* Ablk = A + (size_t)bm * 64 * K;
    const bf16* Bblk = Bt + (size_t)bn * 128 * K;

    int ar[2], ac[2], br[4], bc[4];
#pragma unroll
    for (int i = 0; i < 2; ++i) {
        int g = i * 256 + t;
        ar[i] = g >> 3; ac[i] = ((g & 7) ^ (ar[i] & 7)) * 8;
    }
#pragma unroll
    for (int i = 0; i < 4; ++i) {
        int g = i * 256 + t;
        br[i] = g >> 3; bc[i] = ((g & 7) ^ (br[i] & 7)) * 8;
    }

#pragma unroll
    for (int i = 0; i < 2; ++i)
        async_ld16(Ablk + ar[i] * K + ac[i], &At[0][(i * 256 + t) * 8]);
#pragma unroll
    for (int i = 0; i < 4; ++i)
        async_ld16(Bblk + br[i] * K + bc[i], &Bts[0][(i * 256 + t) * 8]);
    __syncthreads();

    for (int k0 = 0; k0 < K; k0 += 64) {
        const int p = (k0 >> 6) & 1;
        if (k0 + 64 < K) {
            const int q = p ^ 1;
            const int kn = k0 + 64;
#pragma unroll
            for (int i = 0; i < 2; ++i)
                async_ld16(Ablk + ar[i] * K + kn + ac[i], &At[q][(i * 256 + t) * 8]);
#pragma unroll
            for (int i = 0; i < 4; ++i)
                async_ld16(Bblk + br[i] * K + kn + bc[i], &Bts[q][(i * 256 + t) * 8]);
        }

#pragma unroll
        for (int kh = 0; kh < 2; ++kh) {
            short8 af[2], bfr[4];
#pragma unroll
            for (int mt = 0; mt < 2; ++mt) {
                int R = wm * 32 + mt * 16 + n15;
                af[mt] = ld8(&At[p][R * 64 + (((kh * 4 + quad) ^ (R & 7)) * 8)]);
            }
#pragma unroll
            for (int nt = 0; nt < 4; ++nt) {
                int R = wn * 64 + nt * 16 + n15;
                bfr[nt] = ld8(&Bts[p][R * 64 + (((kh * 4 + quad) ^ (R & 7)) * 8)]);
            }
#pragma unroll
            for (int mt = 0; mt < 2; ++mt)
#pragma unroll
                for (int nt = 0; nt < 4; ++nt)
                    acc[mt][nt] = MFMA16(af[mt], bfr[nt], acc[mt][nt]);
        }

        __syncthreads();
    }

#pragma unroll
    for (int mt = 0; mt < 2; ++mt) {
#pragma unroll
        for (int nt = 0; nt < 4; ++nt) {
            int col = bn * 128 + wn * 64 + nt * 16 + n15;
            float bv = bias[col];
#pragma unroll
            for (int r = 0; r < 4; ++r) {
                int row = bm * 64 + wm * 32 + mt * 16 + quad * 4 + r;
                C[(size_t)row * N + col] = acc[mt][nt][r] + bv;
            }
        }
    }
}

// ---------------------------------------------------------------------------
// Flash attention v9: 32x32x16 MFMA, single-buffered K/V staging, and the
// P (C-layout -> B-layout) transform done ENTIRELY IN REGISTERS via
// __shfl_xor(32): in the 32x32 shape only 2 lanes share a q-column, so
// frag m = [h=0 writer's 4 keys | h=1 writer's 4 keys]. No P LDS traffic,
// no lgkm drain. LDS = 32.5 KB (epilogue/split-K combine reuse tile space).
// 512 threads = 4 q-groups(32 q) x 2 key-halves, additive no-max split-K.
// 128 q/block, grid 256, XCD-swizzled.
// Layouts (32x32x16): A/B [idx=lane&31][k=(lane>>5)*8+j];
// C/D col=lane&31, row=(reg&3)+8*(reg>>2)+4*(lane>>5).
// ---------------------------------------------------------------------------
__global__ __launch_bounds__(512, 4) void flash_attn(const bf16* __restrict__ Q,
                                                     const bf16* __restrict__ K,
                                                     const bf16* __restrict__ Vt,
                                                     bf16* __restrict__ O) {
    __shared__ char SMEM[33280];            // 32 KB tiles/scratch + 512 B Lc
    bf16* Kt  = (bf16*)SMEM;                // [kh][64*64] : 16 KB
    bf16* Vte = (bf16*)(SMEM + 16384);      // [kh][64*64] : 16 KB
    float* Lc = (float*)(SMEM + 32768);     // [4][32]

    const int t = threadIdx.x;
    const int wave = t >> 6;            // 0..7
    const int g = wave >> 1;            // q-group 0..3
    const int kh = wave & 1;            // key half
    const int lane = t & 63;
    const int n31 = lane & 31;
    const int half = lane >> 5;

    const int L = blockIdx.x;           // 0..255
    const int bh = L & 15;              // XCD = L%8 -> bh%8: 2 (b,h) per XCD
    const int b = bh >> 3, h = bh & 7;
    const int q0 = (L >> 4) * 128;
    const int qw = q0 + g * 32;

    const bf16* Qp = Q + ((size_t)(b * NQ + qw) * IDIM + h * DHEAD);
    const bf16* Kp = K + ((size_t)b * NKV * IDIM + h * DHEAD)
                       + (size_t)(kh * 1024) * IDIM;
    const bf16* Vp = Vt + (size_t)((b * HEADS + h) * DHEAD) * NKV + kh * 1024;

    // Q B-frags: B[n=q=lane&31][k=d=ks*16 + half*8 + j]
    short8 qa[4];
#pragma unroll
    for (int ks = 0; ks < 4; ++ks)
        qa[ks] = ld8(Qp + n31 * IDIM + ks * 16 + half * 8);

    // staging (per half: 256 threads, slots u and u+256 of 512):
    // slot s -> row r = s>>3, chunk c = (s&7) ^ (r&7)
    const int u = g * 64 + lane;
    const int s0 = u, s1 = u + 256;
    const int r0 = s0 >> 3, c0 = (s0 & 7) ^ (r0 & 7);
    const int r1 = s1 >> 3, c1 = (s1 & 7) ^ (r1 & 7);
    const bf16* kg0 = Kp + r0 * IDIM + c0 * 8;
    const bf16* kg1 = Kp + r1 * IDIM + c1 * 8;
    const bf16* vg0 = Vp + (size_t)r0 * NKV + c0 * 8;
    const bf16* vg1 = Vp + (size_t)r1 * NKV + c1 * 8;
    bf16* kl0 = Kt + kh * 4096 + s0 * 8;
    bf16* kl1 = Kt + kh * 4096 + s1 * 8;
    bf16* vl0 = Vte + kh * 4096 + s0 * 8;
    bf16* vl1 = Vte + kh * 4096 + s1 * 8;

    f32x16 o[2] = {};
    float lsum = 0.f;

    for (int key0 = 0; key0 < 1024; key0 += 64) {
        async_ld16(kg0 + (size_t)key0 * IDIM, kl0);
        async_ld16(kg1 + (size_t)key0 * IDIM, kl1);
        async_ld16(vg0 + key0, vl0);
        async_ld16(vg1 + key0, vl1);
        __syncthreads();   // tiles visible

        // S^T = K * Q^T : 2 key-subtiles of 32, k over d=64 in 4 steps of 16
        f32x16 s[2] = {};
#pragma unroll
        for (int su = 0; su < 2; ++su) {
            const int row = su * 32 + n31;
            const bf16* kr = Kt + kh * 4096 + row * 64;
            const int rs = row & 7;
#pragma unroll
            for (int ks = 0; ks < 4; ++ks) {
                short8 ka = ld8(kr + (((ks * 2 + half) ^ rs) * 8));
                s[su] = MFMA32(ka, qa[ks], s[su]);
            }
        }

        // p = exp(s*SCALE); pack per m = su*4+rg: keys 8m + 4*half + 0..3
        unsigned long long pk[8];
#pragma unroll
        for (int su = 0; su < 2; ++su) {
#pragma unroll
            for (int rg = 0; rg < 4; ++rg) {
                float p0 = __expf(s[su][rg * 4 + 0] * SCALE);
                float p1 = __expf(s[su][rg * 4 + 1] * SCALE);
                float p2 = __expf(s[su][rg * 4 + 2] * SCALE);
                float p3 = __expf(s[su][rg * 4 + 3] * SCALE);
                lsum += (p0 + p1) + (p2 + p3);
                bf16 t4[4] = {__float2bfloat16(p0), __float2bfloat16(p1),
                              __float2bfloat16(p2), __float2bfloat16(p3)};
                pk[su * 4 + rg] = *(unsigned long long*)t4;
            }
        }

        // register P^T transform: frag m = 2*ks2 + half needs
        // lo = h0-writer's pk[m] (keys 8m+0..3), hi = h1-writer's pk[m].
        short8 pb[4];
#pragma unroll
        for (int i = 0; i < 4; ++i) {
            unsigned long long send = half ? pk[2 * i] : pk[2 * i + 1];
            unsigned long long rv = __shfl_xor(send, 32, 64);
            union { unsigned long long u2[2]; short8 v; } U;
            if (half) { U.u2[0] = rv;        U.u2[1] = pk[2 * i + 1]; }
            else      { U.u2[0] = pk[2 * i]; U.u2[1] = rv; }
            pb[i] = U.v;
        }

        // O^T += V^T * P^T : 2 d-subtiles of 32, k over 64 keys
#pragma unroll
        for (int dt = 0; dt < 2; ++dt) {
            const int row = dt * 32 + n31;
            const bf16* vr = Vte + kh * 4096 + row * 64;
            const int rs = row & 7;
#pragma unroll
            for (int ks2 = 0; ks2 < 4; ++ks2) {
                short8 va = ld8(vr + (((ks2 * 2 + half) ^ rs) * 8));
                o[dt] = MFMA32(va, pb[ks2], o[dt]);
            }
        }
        __syncthreads();   // all waves off tiles before restaging
    }

    // per-lane l covers q=n31; lanes x and x+32 hold disjoint key subsets
    lsum += __shfl_xor(lsum, 32, 64);

    // ---- split-K combine (reuses the 32 KB tile region behind barriers) ----
    float* Cg = (float*)SMEM + g * (64 * 32);   // [d=64][q=32] fp32, 8 KB/group
    if (kh == 1) {
#pragma unroll
        for (int dt = 0; dt < 2; ++dt)
#pragma unroll
            for (int r = 0; r < 16; ++r) {
                int d = dt * 32 + (r & 3) + 8 * (r >> 2) + 4 * half;
                Cg[(d << 5) + n31] = o[dt][r];
            }
        if (lane < 32) Lc[g * 32 + lane] = lsum;
    }
    __syncthreads();
    if (kh == 0) {
        float inv = 1.0f / (lsum + Lc[g * 32 + n31]);
#pragma unroll
        for (int dt = 0; dt < 2; ++dt)
#pragma unroll
            for (int r = 0; r < 16; ++r) {
                int d = dt * 32 + (r & 3) + 8 * (r >> 2) + 4 * half;
                o[dt][r] = (o[dt][r] + Cg[(d << 5) + n31]) * inv;
            }
    }
    __syncthreads();   // all Cg reads done before bf16 overwrite
    if (kh == 0) {
        // O^T bf16, row=q stride 64, chunk-swizzled by (n31>>3)
        bf16* Og = (bf16*)SMEM + g * (32 * 64);
#pragma unroll
        for (int dt = 0; dt < 2; ++dt) {
#pragma unroll
            for (int rg = 0; rg < 4; ++rg) {
                bf16 p4[4];
#pragma unroll
                for (int i = 0; i < 4; ++i)
                    p4[i] = __float2bfloat16(o[dt][rg * 4 + i]);
                int chunk = (dt * 4 + rg) ^ (n31 >> 3);
                *(uint2*)&Og[n31 * 64 + chunk * 8 + half * 4] = *(uint2*)p4;
            }
        }
    }
    __syncthreads();

    // coalesced O store: thread t -> q_local = t>>2 (128 rows), 16 d (32 B)
    {
        int ql = t >> 2, seg = t & 3;
        int qr = ql & 31, qg = ql >> 5;
        const bf16* Og = (bf16*)SMEM + qg * (32 * 64);
        int cs = qr >> 3;
        short8 a0 = ld8(&Og[qr * 64 + ((seg * 2) ^ cs) * 8]);
        short8 a1 = ld8(&Og[qr * 64 + ((seg * 2 + 1) ^ cs) * 8]);
        bf16* dst = O + ((size_t)(b * NQ + q0 + ql) * IDIM + h * DHEAD + seg * 16);
        *(short8*)dst = a0;
        *(short8*)(dst + 8) = a1;
    }
}

// ---------------------------------------------------------------------------
extern "C" void kernel_launch(void* const* d_in, const int* in_sizes, int n_in,
                              void* d_out, int out_size, void* d_ws, size_t ws_size,
                              hipStream_t stream) {
    (void)in_sizes; (void)n_in; (void)out_size; (void)ws_size;

    const float* x   = (const float*)d_in[0];   // (2,2048,1024)
    const float* ctx = (const float*)d_in[1];   // (2,2048,768)
    const float* Wq  = (const float*)d_in[2];   // (1024,512)
    const float* Wk  = (const float*)d_in[3];   // (768,512)
    const float* Wv  = (const float*)d_in[4];   // (768,512)
    const float* Wo  = (const float*)d_in[5];   // (512,1024)
    const float* bo  = (const float*)d_in[6];   // (1024,)
    float* out = (float*)d_out;                 // (2,2048,1024) fp32

    char* ws = (char*)d_ws;
    bf16* Xb  = (bf16*)(ws + 0);           // 4096x1024 bf16 : 8,388,608 B
    bf16* Cb  = (bf16*)(ws + 8388608);     // 4096x768  bf16 : 6,291,456 B
    bf16* WqT = (bf16*)(ws + 14680064);    //  512x1024 : 1,048,576 B
    bf16* WkT = (bf16*)(ws + 15728640);    //  512x768  :   786,432 B
    bf16* WvT = (bf16*)(ws + 16515072);    //  512x768  :   786,432 B
    bf16* WoT = (bf16*)(ws + 17301504);    // 1024x512  : 1,048,576 B
    bf16* Qb  = (bf16*)(ws + 18350080);    // 4096x512  : 4,194,304 B
    bf16* Kb  = (bf16*)(ws + 22544384);    // 4096x512  : 4,194,304 B
    bf16* Vt  = (bf16*)(ws + 26738688);    // (2,8,64,2048) : 4,194,304 B
    bf16* Ob  = (bf16*)(ws + 30932992);    // 4096x512  : 4,194,304 B
    // total 35,127,296 B

    prologue<<<4032, 256, 0, stream>>>(x, ctx, Wq, Wk, Wv, Wo,
                                       Xb, Cb, WqT, WkT, WvT, WoT);

    // Q/K/V projections: 64x128 tiles, BK=64, 768 blocks, double-buffered
    qkv_gemm<<<dim3(4, 64, 3), 256, 0, stream>>>(Xb, Cb, WqT, WkT, WvT, Qb, Kb, Vt);

    // attention: 256 blocks x 512 threads, 32x32x16 MFMA, register-P
    flash_attn<<<256, 512, 0, stream>>>(Qb, Kb, Vt, Ob);

    // out = O @ Wo + bo, fp32: 64x128 tiles, BK=64, 512 blocks
    out_gemm<<<dim3(8, 64), 256, 0, stream>>>(Ob, WoT, bo, out);
}

// Round 12
// 149.058 us; speedup vs baseline: 1.0669x; 1.0669x over previous
//
#include <hip/hip_runtime.h>
#include <hip/hip_bf16.h>

typedef __hip_bfloat16 bf16;
typedef __attribute__((ext_vector_type(8))) short short8;
typedef __attribute__((ext_vector_type(4))) float f32x4;

#define MFMA16(a, b, c) __builtin_amdgcn_mfma_f32_16x16x32_bf16((a), (b), (c), 0, 0, 0)

// Problem constants
#define BATCH 2
#define NQ 2048
#define NKV 2048
#define HEADS 8
#define DHEAD 64
#define CQ 1024
#define CK 768
#define IDIM 512   // HEADS*DHEAD
#define SCALE 0.125f

__device__ __forceinline__ short8 ld8(const bf16* p) {
    return *(const short8*)p;
}

// async global->LDS, 16 bytes per lane. LDS dst must be wave-uniform base + lane*16.
__device__ __forceinline__ void async_ld16(const bf16* g, bf16* l) {
    __builtin_amdgcn_global_load_lds((__attribute__((address_space(1))) const void*)g,
                                     (__attribute__((address_space(3))) void*)l,
                                     16, 0, 0);
}

// ---------------------------------------------------------------------------
// Prologue: fp32->bf16 activation pack (blocks 0..3583, 8 floats/thread) +
// tiled weight transpose fp32(R,C) -> bf16(C,R) (blocks 3584..4031).
// ---------------------------------------------------------------------------
__global__ __launch_bounds__(256) void prologue(
    const float* __restrict__ x, const float* __restrict__ ctx,
    const float* __restrict__ Wq, const float* __restrict__ Wk,
    const float* __restrict__ Wv, const float* __restrict__ Wo,
    bf16* __restrict__ Xb, bf16* __restrict__ Cb,
    bf16* __restrict__ WqT, bf16* __restrict__ WkT,
    bf16* __restrict__ WvT, bf16* __restrict__ WoT) {
    __shared__ float tile[64][65];
    const int t = threadIdx.x;
    const int bx = blockIdx.x;

    if (bx < 3584) {
        int idx = bx * 256 + t;
        const int NX8 = (4096 * 1024) / 8;      // 524,288
        const float4* srcp;
        bf16* dstp;
        if (idx < NX8) {
            srcp = (const float4*)x + (size_t)idx * 2;
            dstp = Xb + (size_t)idx * 8;
        } else {
            int j = idx - NX8;                  // < 393,216
            srcp = (const float4*)ctx + (size_t)j * 2;
            dstp = Cb + (size_t)j * 8;
        }
        float4 v0 = srcp[0], v1 = srcp[1];
        bf16 tmp[8] = {__float2bfloat16(v0.x), __float2bfloat16(v0.y),
                       __float2bfloat16(v0.z), __float2bfloat16(v0.w),
                       __float2bfloat16(v1.x), __float2bfloat16(v1.y),
                       __float2bfloat16(v1.z), __float2bfloat16(v1.w)};
        *(short8*)dstp = *(short8*)tmp;
        return;
    }

    int tb = bx - 3584;   // 0..447
    const float* src; bf16* dst; int R, C, ti;
    if (tb < 128)      { src = Wq; dst = WqT; R = 1024; C = 512;  ti = tb; }
    else if (tb < 224) { src = Wk; dst = WkT; R = 768;  C = 512;  ti = tb - 128; }
    else if (tb < 320) { src = Wv; dst = WvT; R = 768;  C = 512;  ti = tb - 224; }
    else               { src = Wo; dst = WoT; R = 512;  C = 1024; ti = tb - 320; }
    const int tilesC = C >> 6;
    const int tr = ti / tilesC, tc = ti - tr * tilesC;

    {
        int row = t >> 4;
        int c4 = (t & 15) * 4;
#pragma unroll
        for (int p = 0; p < 4; ++p) {
            float4 v = *(const float4*)&src[(size_t)(tr * 64 + p * 16 + row) * C + tc * 64 + c4];
            tile[p * 16 + row][c4 + 0] = v.x;
            tile[p * 16 + row][c4 + 1] = v.y;
            tile[p * 16 + row][c4 + 2] = v.z;
            tile[p * 16 + row][c4 + 3] = v.w;
        }
    }
    __syncthreads();
    {
        int oc = t >> 2;
        int r0 = (t & 3) * 16;
        bf16 tmp[16];
#pragma unroll
        for (int j = 0; j < 16; ++j)
            tmp[j] = __float2bfloat16(tile[r0 + j][oc]);
        bf16* dp = dst + (size_t)(tc * 64 + oc) * R + tr * 64 + r0;
        *(short8*)dp = *(short8*)&tmp[0];
        *(short8*)(dp + 8) = *(short8*)&tmp[8];
    }
}

// ---------------------------------------------------------------------------
// Fused Q/K/V projection GEMM, 64x128 tiles, BK=64, XOR-swizzled LDS chunks,
// double-buffered. blockIdx.z: 0 -> Q, 1 -> K, 2 -> V^T epilogue.
// (r8-verified configuration)
// ---------------------------------------------------------------------------
__global__ __launch_bounds__(256) void qkv_gemm(
    const bf16* __restrict__ Xb, const bf16* __restrict__ Cb,
    const bf16* __restrict__ WqT, const bf16* __restrict__ WkT,
    const bf16* __restrict__ WvT,
    bf16* __restrict__ Qb, bf16* __restrict__ Kb, bf16* __restrict__ Vt) {
    __shared__ bf16 At[2][64 * 64];
    __shared__ bf16 Bts[2][128 * 64];

    const int z = blockIdx.z;
    const bf16* A  = (z == 0) ? Xb : Cb;
    const bf16* Bt = (z == 0) ? WqT : (z == 1) ? WkT : WvT;
    const int K = (z == 0) ? 1024 : 768;

    const int t = threadIdx.x;
    const int wave = t >> 6;
    const int lane = t & 63;
    const int n15 = lane & 15;
    const int quad = lane >> 4;
    const int wm = wave >> 1;
    const int wn = wave & 1;
    const int bm = blockIdx.y;     // 0..63
    const int bn = blockIdx.x;     // 0..3

    f32x4 acc[2][4] = {};

    const bf16* Ablk = A + (size_t)bm * 64 * K;
    const bf16* Bblk = Bt + (size_t)bn * 128 * K;

    int ar[2], ac[2], br[4], bc[4];
#pragma unroll
    for (int i = 0; i < 2; ++i) {
        int g = i * 256 + t;
        ar[i] = g >> 3; ac[i] = ((g & 7) ^ (ar[i] & 7)) * 8;
    }
#pragma unroll
    for (int i = 0; i < 4; ++i) {
        int g = i * 256 + t;
        br[i] = g >> 3; bc[i] = ((g & 7) ^ (br[i] & 7)) * 8;
    }

#pragma unroll
    for (int i = 0; i < 2; ++i)
        async_ld16(Ablk + ar[i] * K + ac[i], &At[0][(i * 256 + t) * 8]);
#pragma unroll
    for (int i = 0; i < 4; ++i)
        async_ld16(Bblk + br[i] * K + bc[i], &Bts[0][(i * 256 + t) * 8]);
    __syncthreads();

    for (int k0 = 0; k0 < K; k0 += 64) {
        const int p = (k0 >> 6) & 1;
        if (k0 + 64 < K) {
            const int q = p ^ 1;
            const int kn = k0 + 64;
#pragma unroll
            for (int i = 0; i < 2; ++i)
                async_ld16(Ablk + ar[i] * K + kn + ac[i], &At[q][(i * 256 + t) * 8]);
#pragma unroll
            for (int i = 0; i < 4; ++i)
                async_ld16(Bblk + br[i] * K + kn + bc[i], &Bts[q][(i * 256 + t) * 8]);
        }

#pragma unroll
        for (int kh = 0; kh < 2; ++kh) {
            short8 af[2], bfr[4];
#pragma unroll
            for (int mt = 0; mt < 2; ++mt) {
                int R = wm * 32 + mt * 16 + n15;
                af[mt] = ld8(&At[p][R * 64 + (((kh * 4 + quad) ^ (R & 7)) * 8)]);
            }
#pragma unroll
            for (int nt = 0; nt < 4; ++nt) {
                int R = wn * 64 + nt * 16 + n15;
                bfr[nt] = ld8(&Bts[p][R * 64 + (((kh * 4 + quad) ^ (R & 7)) * 8)]);
            }
#pragma unroll
            for (int mt = 0; mt < 2; ++mt)
#pragma unroll
                for (int nt = 0; nt < 4; ++nt)
                    acc[mt][nt] = MFMA16(af[mt], bfr[nt], acc[mt][nt]);
        }

        __syncthreads();
    }

    bf16* C = (z == 0) ? Qb : (z == 1) ? Kb : Vt;
#pragma unroll
    for (int mt = 0; mt < 2; ++mt) {
#pragma unroll
        for (int nt = 0; nt < 4; ++nt) {
            int col = bn * 128 + wn * 64 + nt * 16 + n15;
#pragma unroll
            for (int r = 0; r < 4; ++r) {
                int row = bm * 64 + wm * 32 + mt * 16 + quad * 4 + r;
                bf16 v = __float2bfloat16(acc[mt][nt][r]);
                if (z < 2) {
                    C[(size_t)row * 512 + col] = v;
                } else {
                    int b = row >> 11, j = row & 2047;
                    int h = col >> 6, d = col & 63;
                    C[(size_t)(((b << 3) + h) * 64 + d) * 2048 + j] = v;
                }
            }
        }
    }
}

// ---------------------------------------------------------------------------
// Final GEMM: out(4096,1024) = Ob(4096,512) @ WoT(1024,512)^T + bo, fp32 out.
// 64x128 tiles, BK=64, swizzled, double-buffered (r8) + NEW: coalesced fp32
// epilogue via LDS transpose (aliased over At/Bts, stride 132 = 2-way free).
// ---------------------------------------------------------------------------
__global__ __launch_bounds__(256) void out_gemm(const bf16* __restrict__ A,
                                                const bf16* __restrict__ Bt,
                                                const float* __restrict__ bias,
                                                float* __restrict__ C) {
    const int K = 512, N = 1024;
    __shared__ char SMEM[49152];               // 48 KB: At 16 + Bts 32
    bf16* At  = (bf16*)SMEM;                   // [2][64*64]
    bf16* Bts = (bf16*)(SMEM + 16384);         // [2][128*64]
    float* Ep = (float*)SMEM;                  // epilogue: [64][132] = 33.8 KB

    const int t = threadIdx.x;
    const int wave = t >> 6;
    const int lane = t & 63;
    const int n15 = lane & 15;
    const int quad = lane >> 4;
    const int wm = wave >> 1;
    const int wn = wave & 1;
    const int bm = blockIdx.y;     // 0..63
    const int bn = blockIdx.x;     // 0..7

    f32x4 acc[2][4] = {};

    const bf16* Ablk = A + (size_t)bm * 64 * K;
    const bf16* Bblk = Bt + (size_t)bn * 128 * K;

    int ar[2], ac[2], br[4], bc[4];
#pragma unroll
    for (int i = 0; i < 2; ++i) {
        int g = i * 256 + t;
        ar[i] = g >> 3; ac[i] = ((g & 7) ^ (ar[i] & 7)) * 8;
    }
#pragma unroll
    for (int i = 0; i < 4; ++i) {
        int g = i * 256 + t;
        br[i] = g >> 3; bc[i] = ((g & 7) ^ (br[i] & 7)) * 8;
    }

#pragma unroll
    for (int i = 0; i < 2; ++i)
        async_ld16(Ablk + ar[i] * K + ac[i], At + (i * 256 + t) * 8);
#pragma unroll
    for (int i = 0; i < 4; ++i)
        async_ld16(Bblk + br[i] * K + bc[i], Bts + (i * 256 + t) * 8);
    __syncthreads();

    for (int k0 = 0; k0 < K; k0 += 64) {
        const int p = (k0 >> 6) & 1;
        if (k0 + 64 < K) {
            const int q = p ^ 1;
            const int kn = k0 + 64;
#pragma unroll
            for (int i = 0; i < 2; ++i)
                async_ld16(Ablk + ar[i] * K + kn + ac[i], At + q * 4096 + (i * 256 + t) * 8);
#pragma unroll
            for (int i = 0; i < 4; ++i)
                async_ld16(Bblk + br[i] * K + kn + bc[i], Bts + q * 8192 + (i * 256 + t) * 8);
        }

#pragma unroll
        for (int kh = 0; kh < 2; ++kh) {
            short8 af[2], bfr[4];
#pragma unroll
            for (int mt = 0; mt < 2; ++mt) {
                int R = wm * 32 + mt * 16 + n15;
                af[mt] = ld8(At + p * 4096 + R * 64 + (((kh * 4 + quad) ^ (R & 7)) * 8));
            }
#pragma unroll
            for (int nt = 0; nt < 4; ++nt) {
                int R = wn * 64 + nt * 16 + n15;
                bfr[nt] = ld8(Bts + p * 8192 + R * 64 + (((kh * 4 + quad) ^ (R & 7)) * 8));
            }
#pragma unroll
            for (int mt = 0; mt < 2; ++mt)
#pragma unroll
                for (int nt = 0; nt < 4; ++nt)
                    acc[mt][nt] = MFMA16(af[mt], bfr[nt], acc[mt][nt]);
        }

        __syncthreads();
    }

    // stage fp32 tile to LDS (MFMA C-layout -> row-major), stride 132
#pragma unroll
    for (int mt = 0; mt < 2; ++mt)
#pragma unroll
        for (int nt = 0; nt < 4; ++nt) {
            int col = wn * 64 + nt * 16 + n15;
#pragma unroll
            for (int r = 0; r < 4; ++r) {
                int row = wm * 32 + mt * 16 + quad * 4 + r;
                Ep[row * 132 + col] = acc[mt][nt][r];
            }
        }
    __syncthreads();

    // coalesced store: 8 float4 per thread, consecutive lanes -> consecutive 16B
#pragma unroll
    for (int i = 0; i < 8; ++i) {
        int f4 = i * 256 + t;
        int row = f4 >> 5;            // 0..63
        int c4 = (f4 & 31) * 4;       // 0..124
        float4 v = *(float4*)&Ep[row * 132 + c4];
        float4 bv = *(const float4*)&bias[bn * 128 + c4];
        v.x += bv.x; v.y += bv.y; v.z += bv.z; v.w += bv.w;
        *(float4*)&C[(size_t)(bm * 64 + row) * N + bn * 128 + c4] = v;
    }
}

// ---------------------------------------------------------------------------
// Flash attention (r8-verified, best measured ~30 us = its DS floor):
// 64 q/block-row-group, 16 q/wave, transposed-S, LDS-staged swizzled K/V,
// 512 threads = 4 q-groups x 2 key-halves (in-block split-K, additive no-max
// partials, LDS combine). Grid 512 -> 2 blocks/CU x 8 waves = 16 waves/CU.
// Q:(b,i,h,d)  K:(b,j,h,d)  Vt:(b,h,d,j)  O:(b,i,h,d)
// ---------------------------------------------------------------------------
__global__ __launch_bounds__(512, 1) void flash_attn(const bf16* __restrict__ Q,
                                                     const bf16* __restrict__ K,
                                                     const bf16* __restrict__ Vt,
                                                     bf16* __restrict__ O) {
    __shared__ bf16 Kt[2][64 * 64];     // per key-half swizzled K tile
    __shared__ bf16 Vte[2][64 * 64];    // per key-half swizzled V^T tile
    __shared__ bf16 Pa[8][16 * 72];     // per-wave P / O-transpose area
    __shared__ float Oc[4][64][16];     // [g][d][q] half-1 partial O
    __shared__ float Lc[4][16];         // [g][q]    half-1 partial l

    const int t = threadIdx.x;
    const int wave = t >> 6;            // 0..7
    const int g = wave >> 1;            // q-group 0..3
    const int khalf = wave & 1;         // key half
    const int lane = t & 63;
    const int n15 = lane & 15;
    const int quad = lane >> 4;

    const int L = blockIdx.x;           // 0..511
    const int bh = L & 15;              // XCD = L%8 -> bh%8: 2 (b,h) per XCD
    const int b = bh >> 3, h = bh & 7;
    const int q0 = (L >> 4) * 64;
    const int qw = q0 + g * 16;

    const bf16* Qp = Q + ((size_t)(b * NQ + qw) * IDIM + h * DHEAD);
    const bf16* Kp = K + ((size_t)b * NKV * IDIM + h * DHEAD)
                       + (size_t)(khalf * 1024) * IDIM;
    const bf16* Vp = Vt + (size_t)((b * HEADS + h) * DHEAD) * NKV + khalf * 1024;
    bf16* Pw = Pa[wave];

    // Q fragments (B-operand): B[n=q=lane&15][k=d=quad*8+j], two 32-d halves
    short8 qa0 = ld8(Qp + n15 * IDIM + quad * 8);
    short8 qa1 = ld8(Qp + n15 * IDIM + 32 + quad * 8);

    // staging (256 lanes per half): slot s -> row r = s>>3, chunk c = (s&7)^(r&7)
    const int s0 = g * 128 + lane;
    const int s1 = s0 + 64;
    const int r0 = s0 >> 3, c0 = (s0 & 7) ^ (r0 & 7);
    const int r1 = s1 >> 3, c1 = (s1 & 7) ^ (r1 & 7);
    const bf16* kg0 = Kp + r0 * IDIM + c0 * 8;
    const bf16* kg1 = Kp + r1 * IDIM + c1 * 8;
    const bf16* vg0 = Vp + (size_t)r0 * NKV + c0 * 8;
    const bf16* vg1 = Vp + (size_t)r1 * NKV + c1 * 8;
    bf16* kl0 = &Kt[khalf][s0 * 8];
    bf16* kl1 = &Kt[khalf][s1 * 8];
    bf16* vl0 = &Vte[khalf][s0 * 8];
    bf16* vl1 = &Vte[khalf][s1 * 8];

    f32x4 o[4] = {};
    float lsum = 0.f;
    const int sw = n15 & 7;

    for (int key0 = 0; key0 < 1024; key0 += 64) {
        async_ld16(kg0 + (size_t)key0 * IDIM, kl0);
        async_ld16(kg1 + (size_t)key0 * IDIM, kl1);
        async_ld16(vg0 + key0, vl0);
        async_ld16(vg1 + key0, vl1);
        __syncthreads();   // tiles visible

        // S^T = K * Q^T : A=K frag A[m=key16][k=d], B=Q. 4 key-subtiles.
        f32x4 s[4] = {};
#pragma unroll
        for (int su = 0; su < 4; ++su) {
            const bf16* kr = &Kt[khalf][(su * 16 + n15) * 64];
            short8 ka0 = ld8(kr + ((quad ^ sw) * 8));
            short8 ka1 = ld8(kr + (((4 + quad) ^ sw) * 8));
            s[su] = MFMA16(ka0, qa0, s[su]);
            s[su] = MFMA16(ka1, qa1, s[su]);
        }

        // p = exp(s*SCALE); per-lane l partial; P^T[q][key] packed b64 stores
#pragma unroll
        for (int su = 0; su < 4; ++su) {
            float p0 = __expf(s[su][0] * SCALE);
            float p1 = __expf(s[su][1] * SCALE);
            float p2 = __expf(s[su][2] * SCALE);
            float p3 = __expf(s[su][3] * SCALE);
            lsum += (p0 + p1) + (p2 + p3);
            bf16 pk[4] = {__float2bfloat16(p0), __float2bfloat16(p1),
                          __float2bfloat16(p2), __float2bfloat16(p3)};
            *(uint2*)&Pw[n15 * 72 + su * 16 + quad * 4] = *(uint2*)pk;
        }
        // in-wave DS ordering: drain LDS writes before re-reading (no vmcnt!)
        asm volatile("s_waitcnt lgkmcnt(0)" ::: "memory");

        // P^T as B-operand: B[n=q=n15][k=key=quad*8+j], two 32-key halves
        short8 pb0 = ld8(&Pw[n15 * 72 + quad * 8]);
        short8 pb1 = ld8(&Pw[n15 * 72 + 32 + quad * 8]);

        // O^T += V^T * P^T : A=V frag A[m=d16][k=key]
#pragma unroll
        for (int d4 = 0; d4 < 4; ++d4) {
            const bf16* vr = &Vte[khalf][(d4 * 16 + n15) * 64];
            short8 va0 = ld8(vr + ((quad ^ sw) * 8));
            short8 va1 = ld8(vr + (((4 + quad) ^ sw) * 8));
            o[d4] = MFMA16(va0, pb0, o[d4]);
            o[d4] = MFMA16(va1, pb1, o[d4]);
        }
        __syncthreads();   // all waves off tiles before restaging
    }

    // per-wave l reduction over quads -> all lanes of same n15 hold l[q]
    lsum += __shfl_xor(lsum, 16, 64);
    lsum += __shfl_xor(lsum, 32, 64);

    // combine key halves (additive partials — no max subtraction)
    if (khalf == 1) {
#pragma unroll
        for (int d4 = 0; d4 < 4; ++d4)
#pragma unroll
            for (int r = 0; r < 4; ++r)
                Oc[g][d4 * 16 + quad * 4 + r][n15] = o[d4][r];
        if (quad == 0) Lc[g][n15] = lsum;
    }
    __syncthreads();
    if (khalf == 0) {
        float lt = lsum + Lc[g][n15];
        float inv = 1.0f / lt;
#pragma unroll
        for (int d4 = 0; d4 < 4; ++d4) {
            bf16 pk[4];
#pragma unroll
            for (int r = 0; r < 4; ++r) {
                float v = o[d4][r] + Oc[g][d4 * 16 + quad * 4 + r][n15];
                pk[r] = __float2bfloat16(v * inv);
            }
            *(uint2*)&Pa[g][n15 * 72 + d4 * 16 + quad * 4] = *(uint2*)pk;
        }
    }
    __syncthreads();

    // coalesced O store: thread t -> q_local = t>>3 (64 rows), 8 d-elems (16B)
    {
        int ql = t >> 3, seg = t & 7;
        const bf16* src = &Pa[ql >> 4][(ql & 15) * 72 + seg * 8];
        short8 a0 = ld8(src);
        bf16* dst = O + ((size_t)(b * NQ + q0 + ql) * IDIM + h * DHEAD + seg * 8);
        *(short8*)dst = a0;
    }
}

// ---------------------------------------------------------------------------
extern "C" void kernel_launch(void* const* d_in, const int* in_sizes, int n_in,
                              void* d_out, int out_size, void* d_ws, size_t ws_size,
                              hipStream_t stream) {
    (void)in_sizes; (void)n_in; (void)out_size; (void)ws_size;

    const float* x   = (const float*)d_in[0];   // (2,2048,1024)
    const float* ctx = (const float*)d_in[1];   // (2,2048,768)
    const float* Wq  = (const float*)d_in[2];   // (1024,512)
    const float* Wk  = (const float*)d_in[3];   // (768,512)
    const float* Wv  = (const float*)d_in[4];   // (768,512)
    const float* Wo  = (const float*)d_in[5];   // (512,1024)
    const float* bo  = (const float*)d_in[6];   // (1024,)
    float* out = (float*)d_out;                 // (2,2048,1024) fp32

    char* ws = (char*)d_ws;
    bf16* Xb  = (bf16*)(ws + 0);           // 4096x1024 bf16 : 8,388,608 B
    bf16* Cb  = (bf16*)(ws + 8388608);     // 4096x768  bf16 : 6,291,456 B
    bf16* WqT = (bf16*)(ws + 14680064);    //  512x1024 : 1,048,576 B
    bf16* WkT = (bf16*)(ws + 15728640);    //  512x768  :   786,432 B
    bf16* WvT = (bf16*)(ws + 16515072);    //  512x768  :   786,432 B
    bf16* WoT = (bf16*)(ws + 17301504);    // 1024x512  : 1,048,576 B
    bf16* Qb  = (bf16*)(ws + 18350080);    // 4096x512  : 4,194,304 B
    bf16* Kb  = (bf16*)(ws + 22544384);    // 4096x512  : 4,194,304 B
    bf16* Vt  = (bf16*)(ws + 26738688);    // (2,8,64,2048) : 4,194,304 B
    bf16* Ob  = (bf16*)(ws + 30932992);    // 4096x512  : 4,194,304 B
    // total 35,127,296 B

    prologue<<<4032, 256, 0, stream>>>(x, ctx, Wq, Wk, Wv, Wo,
                                       Xb, Cb, WqT, WkT, WvT, WoT);

    // Q/K/V projections: 64x128 tiles, BK=64, 768 blocks, double-buffered
    qkv_gemm<<<dim3(4, 64, 3), 256, 0, stream>>>(Xb, Cb, WqT, WkT, WvT, Qb, Kb, Vt);

    // attention: 512 blocks x 512 threads (8 waves: 4 q-groups x 2 key-halves)
    flash_attn<<<512, 512, 0, stream>>>(Qb, Kb, Vt, Ob);

    // out = O @ Wo + bo, fp32: 64x128 tiles, BK=64, 512 blocks
    out_gemm<<<dim3(8, 64), 256, 0, stream>>>(Ob, WoT, bo, out);
}